// Round 15
// baseline (275.788 us; speedup 1.0000x reference)
//
#include <hip/hip_runtime.h>
#include <hip/hip_bf16.h>

// Transformer encoder layer (post-LN), B=2 S=2048 D=1024 H=16 DH=64 FF=4096.
// m97-family 128^2 bf16 MFMA GEMMs with BK=64 + granule-XOR LDS swizzle
// (halved barrier-drain count, conflict-free ds_read_b128) + 8-warp 32x32
// swapped-QK^T flash attention (mask folded into QK^T MFMA as rank-1 bias,
// MFMA denominator, defer-max) + fp32 LN with fused split-K reduce.

typedef __bf16 bf16;
typedef __bf16 bf16x8 __attribute__((ext_vector_type(8)));
typedef __bf16 bf16x4 __attribute__((ext_vector_type(4)));
typedef float  f32x4  __attribute__((ext_vector_type(4)));
typedef float  f32x16 __attribute__((ext_vector_type(16)));
typedef unsigned u32x2 __attribute__((ext_vector_type(2)));
typedef unsigned u32x4 __attribute__((ext_vector_type(4)));

#define DEVI __device__ __forceinline__

constexpr int S_LEN  = 2048;
constexpr int NTOK   = 4096;   // B*S
constexpr int DMODEL = 1024;
constexpr int NFF    = 4096;
constexpr float SCALE2 = 0.125f * 1.44269504088896f;  // (1/sqrt(64)) * log2(e)

DEVI void gld16(const void* g, void* l) {
  __builtin_amdgcn_global_load_lds((const __attribute__((address_space(1))) void*)g,
                                   (__attribute__((address_space(3))) void*)l, 16, 0, 0);
}

DEVI f32x4 mfma16(bf16x8 a, bf16x8 b, f32x4 c) {
  return __builtin_amdgcn_mfma_f32_16x16x32_bf16(a, b, c, 0, 0, 0);
}
DEVI f32x16 mfma32(bf16x8 a, bf16x8 b, f32x16 c) {
  return __builtin_amdgcn_mfma_f32_32x32x16_bf16(a, b, c, 0, 0, 0);
}
DEVI unsigned cvtpk(float lo, float hi) {
  unsigned d;
  asm("v_cvt_pk_bf16_f32 %0, %1, %2" : "=v"(d) : "v"(lo), "v"(hi));
  return d;
}
DEVI void plswap(unsigned &a, unsigned &b) {
#if __has_builtin(__builtin_amdgcn_permlane32_swap)
  u32x2 r = __builtin_amdgcn_permlane32_swap(a, b, false, false);
  a = r[0]; b = r[1];
#else
  asm volatile("v_permlane32_swap_b32 %0, %1" : "+v"(a), "+v"(b));
#endif
}
DEVI float fexp2(float x) {
#if __has_builtin(__builtin_amdgcn_exp2f)
  return __builtin_amdgcn_exp2f(x);
#else
  return exp2f(x);
#endif
}
#define M3(a, b, c) fmaxf(fmaxf(a, b), c)

// ---------------------------------------------------------------------------
// GEMM: C[M,N] = A[M,ld] @ Bt[N,ld]^T over K-chunk [kz*Kc,(kz+1)*Kc).
// 128x128 tile, BK=64 (16 barriers per K=1024 vs 32 at BK=32), 4 waves
// (2x2 of 64x64). LDS [128][64] per operand (32KB total), granule-XOR
// swizzle: LDS row r granule slot g holds global granule g ^ swz3(r),
// swz3(r) = (r ^ (r>>3)) & 7 — linear gload_lds dest + inverse-swizzled
// global src + swizzled ds_read (conflict-free b128, 2 lanes/bank).
// 1D grid, XCD-bijective swizzle.
// MODE 0: bf16 out = fused-QKV scatter (q scaled by SCALE2; v written ^T)
// MODE 3: bf16 out = relu(acc + bias[col]), row-major [M][N]
// MODE 4: f32 partial out[kz][M][N] = acc  (reduce fused into ln_k)
// ---------------------------------------------------------------------------
template <int MODE>
__global__ __launch_bounds__(256) void gemm_bt(
    const bf16* __restrict__ A, const bf16* __restrict__ Bt,
    void* __restrict__ out, const float* __restrict__ bias,
    int M, int N, int ld, int Kc, int nx, int ny)
{
  __shared__ bf16 As[128 * 64];
  __shared__ bf16 Bs[128 * 64];
  const int tid  = threadIdx.x;
  const int lane = tid & 63, w = tid >> 6;
  const int wr = w >> 1, wc = w & 1;
  const int li16 = lane & 15, hi4 = lane >> 4;

  // XCD-bijective remap (ny % 8 == 0 for all our shapes)
  const int id  = blockIdx.x;
  const int xcd = id & 7;
  int t2 = id >> 3;
  const int bx = t2 % nx;  t2 /= nx;
  const int ppx = ny >> 3;
  const int kz = t2 / ppx;
  const int by = xcd * ppx + (t2 % ppx);
  const int brow = by * 128, bcol = bx * 128;

  // staging: wave w covers rows w*32..w*32+31 in 4 gld16 (8 rows each);
  // global source col pre-swizzled by the row's granule XOR.
  const bf16* Ag[4];
  const bf16* Bg[4];
#pragma unroll
  for (int i = 0; i < 4; ++i) {
    const int r = w * 32 + i * 8 + (lane >> 3);
    const int sl = (lane & 7) ^ ((r ^ (r >> 3)) & 7);
    Ag[i] = A  + (size_t)(brow + r) * ld + kz * Kc + sl * 8;
    Bg[i] = Bt + (size_t)(bcol + r) * ld + kz * Kc + sl * 8;
  }
  bf16* AsW = As + w * 2048;
  bf16* BsW = Bs + w * 2048;

  f32x4 acc[4][4] = {};

  for (int k0 = 0; k0 < Kc; k0 += 64) {
#pragma unroll
    for (int i = 0; i < 4; ++i) {
      gld16(Ag[i] + k0, AsW + i * 512);
      gld16(Bg[i] + k0, BsW + i * 512);
    }
    __syncthreads();

    bf16x8 af[4][2], bfr[4][2];
#pragma unroll
    for (int m = 0; m < 4; ++m) {
      const int row = wr * 64 + m * 16 + li16;
      const int sz = (row ^ (row >> 3)) & 7;
      const bf16* rp = As + row * 64;
#pragma unroll
      for (int ks = 0; ks < 2; ++ks)
        af[m][ks] = *(const bf16x8*)(rp + ((ks * 4 + hi4) ^ sz) * 8);
    }
#pragma unroll
    for (int n = 0; n < 4; ++n) {
      const int row = wc * 64 + n * 16 + li16;
      const int sz = (row ^ (row >> 3)) & 7;
      const bf16* rp = Bs + row * 64;
#pragma unroll
      for (int ks = 0; ks < 2; ++ks)
        bfr[n][ks] = *(const bf16x8*)(rp + ((ks * 4 + hi4) ^ sz) * 8);
    }
    __builtin_amdgcn_s_setprio(1);
#pragma unroll
    for (int m = 0; m < 4; ++m)
#pragma unroll
      for (int n = 0; n < 4; ++n)
#pragma unroll
        for (int ks = 0; ks < 2; ++ks)
          acc[m][n] = mfma16(af[m][ks], bfr[n][ks], acc[m][n]);
    __builtin_amdgcn_s_setprio(0);
    __syncthreads();
  }

  const size_t plane = (size_t)NTOK * DMODEL;
#pragma unroll
  for (int m = 0; m < 4; ++m)
#pragma unroll
    for (int n = 0; n < 4; ++n)
#pragma unroll
      for (int r = 0; r < 4; ++r) {
        const int row = brow + wr * 64 + m * 16 + hi4 * 4 + r;
        const int col = bcol + wc * 64 + n * 16 + li16;
        const float v = acc[m][n][r];
        if (MODE == 0) {
          const int b = row >> 11, s = row & 2047;
          const int which = col >> 10, c = col & 1023, h = c >> 6, d = c & 63;
          bf16* qkv = (bf16*)out;
          if (which == 0)
            qkv[(((size_t)(b * 16 + h)) * 2048 + s) * 64 + d] = (bf16)(v * SCALE2);
          else if (which == 1)
            (qkv + plane)[(((size_t)(b * 16 + h)) * 2048 + s) * 64 + d] = (bf16)v;
          else
            (qkv + 2 * plane)[(((size_t)(b * 16 + h)) * 64 + d) * 2048 + s] = (bf16)v;
        } else if (MODE == 3) {
          const float t = v + bias[col];
          ((bf16*)out)[(size_t)row * N + col] = (bf16)fmaxf(t, 0.0f);
        } else {
          ((float*)out)[(size_t)kz * M * N + (size_t)row * N + col] = v;
        }
      }
}

// ---------------------------------------------------------------------------
// Flash attention, 8 warps x 32 q-rows, KVBLK=64, swapped QK^T (32x32 MFMA).
// 1D grid 256, XCD-affine heads. q pre-scaled. Mask folded into QK^T MFMA as
// rank-1 bias (A=bias[key], B=ones). MFMA denominator; defer-max.
// mbp[b][kt][li] = packed bf16 bias pair (key=kt*64+li, key=kt*64+32+li).
// ---------------------------------------------------------------------------
__global__ __launch_bounds__(512) void attn_k(
    const bf16* __restrict__ q, const bf16* __restrict__ k,
    const bf16* __restrict__ vt, const unsigned* __restrict__ mbp,
    bf16* __restrict__ ctx)
{
  __shared__ __align__(16) char smem[36864];   // K dbuf 16K | V dbuf 16K ; epi
  bf16* Kl = (bf16*)smem;                      // [2][64*64]
  bf16* Vl = (bf16*)(smem + 16384);            // [2][64*64]
  const int tid = threadIdx.x, lane = tid & 63, w = tid >> 6;
  const int hi = lane >> 5, li = lane & 31;
  const int id = blockIdx.x;
  const int j = id >> 3;
  const int bh = (id & 7) * 4 + (j & 3);       // XCD (id&7) owns heads 4*xcd..+3
  const int b = bh >> 4, h = bh & 15;
  const int qbase = (j >> 2) * 256 + w * 32;

  bf16x8 qf[4];
  {
    const bf16* qp = q + ((size_t)bh * S_LEN + qbase + li) * 64 + hi * 8;
#pragma unroll
    for (int c = 0; c < 4; ++c) qf[c] = *(const bf16x8*)(qp + c * 16);
  }
  const u32x4 onesu = {0x3F803F80u, 0x3F803F80u, 0x3F803F80u, 0x3F803F80u};
  const bf16x8 onesv = __builtin_bit_cast(bf16x8, onesu);
  // B operand for the rank-1 mask bias: B[k=0][q]=1 (lanes hi==0, elem 0)
  const u32x4 bq1 = {hi ? 0u : 0x3F80u, 0u, 0u, 0u};
  const bf16x8 bones = __builtin_bit_cast(bf16x8, bq1);

  f32x16 o[2] = {};
  f32x16 acc1 = {};                  // element 0 = softmax denominator (q = li)
  float mrun = -3.0e38f;

  const int srow = w * 8 + (lane >> 3);
  const int sslot = (lane & 7) ^ ((srow ^ (srow >> 3)) & 7);
  const bf16* kg = k  + ((size_t)bh * S_LEN + srow) * 64 + sslot * 8;
  const bf16* vg = vt + ((size_t)bh * 64 + srow) * S_LEN + sslot * 8;

  gld16(kg, Kl + w * 512);
  gld16(vg, Vl + w * 512);
  __syncthreads();

  int buf = 0;
  for (int kt = 0; kt < 32; ++kt) {
    const int nb = buf ^ 1;
    if (kt + 1 < 32) {
      gld16(kg + (size_t)(kt + 1) * 4096, Kl + nb * 4096 + w * 512);
      gld16(vg + (kt + 1) * 64,           Vl + nb * 4096 + w * 512);
    }
    const unsigned mbw = mbp[b * 1024 + kt * 32 + li];
    const bf16* Kb = Kl + buf * 4096;
    const bf16* Vb = Vl + buf * 4096;

    float sc[2][16];
#pragma unroll
    for (int kblk = 0; kblk < 2; ++kblk) {
      const int key = kblk * 32 + li;
      const unsigned swb = ((key ^ (key >> 3)) & 7) << 4;
      const char* kr = (const char*)Kb + key * 128;
      // rank-1 mask bias: st = bias[key] broadcast over q
      const unsigned hw = kblk ? (mbw >> 16) : (mbw & 0xffffu);
      const u32x4 aq = {hi ? 0u : hw, 0u, 0u, 0u};
      f32x16 st = mfma32(__builtin_bit_cast(bf16x8, aq), bones, (f32x16){});
      __builtin_amdgcn_s_setprio(1);
#pragma unroll
      for (int c = 0; c < 4; ++c) {
        const bf16x8 kf = *(const bf16x8*)(kr + ((unsigned)(c * 32 + hi * 16) ^ swb));
        st = mfma32(kf, qf[c], st);
      }
      __builtin_amdgcn_s_setprio(0);
#pragma unroll
      for (int r = 0; r < 16; ++r) sc[kblk][r] = st[r];
    }

    const float* sf = &sc[0][0];
    float m0[11];
#pragma unroll
    for (int i3 = 0; i3 < 10; ++i3) m0[i3] = M3(sf[i3 * 3], sf[i3 * 3 + 1], sf[i3 * 3 + 2]);
    m0[10] = fmaxf(sf[30], sf[31]);
    float tm = fmaxf(fmaxf(M3(m0[0], m0[1], m0[2]), M3(m0[3], m0[4], m0[5])),
                     fmaxf(M3(m0[6], m0[7], m0[8]), fmaxf(m0[9], m0[10])));
    tm = fmaxf(tm, __shfl_xor(tm, 32, 64));

    if (!__all(tm <= mrun + 11.0f)) {
      const float mnew = fmaxf(mrun, tm);
      const float alpha = fexp2(mrun - mnew);
      mrun = mnew;
      o[0] *= alpha;
      o[1] *= alpha;
      acc1[0] = acc1[0] * alpha;
    }
#pragma unroll
    for (int kblk = 0; kblk < 2; ++kblk)
#pragma unroll
      for (int r = 0; r < 16; ++r)
        sc[kblk][r] = fexp2(sc[kblk][r] - mrun);

    bf16x8 pa[4];
#pragma unroll
    for (int kblk = 0; kblk < 2; ++kblk)
#pragma unroll
      for (int hf = 0; hf < 2; ++hf) {
        unsigned A = cvtpk(sc[kblk][hf * 8 + 0], sc[kblk][hf * 8 + 1]);
        unsigned B = cvtpk(sc[kblk][hf * 8 + 2], sc[kblk][hf * 8 + 3]);
        unsigned C = cvtpk(sc[kblk][hf * 8 + 4], sc[kblk][hf * 8 + 5]);
        unsigned D = cvtpk(sc[kblk][hf * 8 + 6], sc[kblk][hf * 8 + 7]);
        plswap(A, C);
        plswap(B, D);
        const u32x4 t = {A, B, C, D};
        pa[kblk * 2 + hf] = __builtin_bit_cast(bf16x8, t);
      }

#pragma unroll
    for (int dblk = 0; dblk < 2; ++dblk) {
      const int d = dblk * 32 + li;
      const unsigned swb = ((d ^ (d >> 3)) & 7) << 4;
      const char* vr = (const char*)Vb + d * 128;
      __builtin_amdgcn_s_setprio(1);
#pragma unroll
      for (int ch = 0; ch < 4; ++ch) {
        const bf16x8 vf = *(const bf16x8*)(vr + ((unsigned)(ch * 32 + hi * 16) ^ swb));
        o[dblk] = mfma32(vf, pa[ch], o[dblk]);
      }
      __builtin_amdgcn_s_setprio(0);
    }
#pragma unroll
    for (int ch = 0; ch < 4; ++ch) acc1 = mfma32(onesv, pa[ch], acc1);
    __syncthreads();
    buf = nb;
  }

  const float rl = 1.0f / acc1[0];
  char* Ep = smem + w * 4608;
#pragma unroll
  for (int dblk = 0; dblk < 2; ++dblk)
#pragma unroll
    for (int g = 0; g < 4; ++g) {
      const unsigned lo = cvtpk(o[dblk][4 * g + 0] * rl, o[dblk][4 * g + 1] * rl);
      const unsigned hw = cvtpk(o[dblk][4 * g + 2] * rl, o[dblk][4 * g + 3] * rl);
      const int d0 = 8 * g + 4 * hi + 32 * dblk;
      *(unsigned long long*)(Ep + li * 144 + d0 * 2) =
          ((unsigned long long)hw << 32) | (unsigned long long)lo;
    }
#pragma unroll
  for (int i = 0; i < 4; ++i) {
    const int r = (lane >> 3) + 8 * i;
    const bf16x8 vv = *(const bf16x8*)(Ep + r * 144 + (lane & 7) * 16);
    *(bf16x8*)(ctx + ((size_t)b * S_LEN + qbase + r) * DMODEL + h * 64 + (lane & 7) * 8) = vv;
  }
}

// ---------------------------------------------------------------------------
// LayerNorm over D=1024 with fused split-K reduce + bias + residual.
// RB=1: residual is bf16. grid = 4096 rows, block = 256 (float4 per thread).
// ---------------------------------------------------------------------------
template <int NPART, int RB>
__global__ __launch_bounds__(256) void ln_k(
    const float* __restrict__ parts, const float* __restrict__ bias,
    const void* __restrict__ resid, const float* __restrict__ gam,
    const float* __restrict__ bet, float* __restrict__ of, bf16* __restrict__ ob)
{
  const int row = blockIdx.x, t = threadIdx.x;
  float4 v = ((const float4*)(parts + (size_t)row * DMODEL))[t];
#pragma unroll
  for (int p = 1; p < NPART; ++p) {
    const float4 u = ((const float4*)(parts + ((size_t)p * NTOK + row) * DMODEL))[t];
    v.x += u.x; v.y += u.y; v.z += u.z; v.w += u.w;
  }
  {
    const float4 b4 = ((const float4*)bias)[t];
    float4 r4;
    if (RB) {
      const bf16x4 rb = *(const bf16x4*)((const bf16*)resid + (size_t)row * DMODEL + t * 4);
      r4.x = (float)rb[0]; r4.y = (float)rb[1]; r4.z = (float)rb[2]; r4.w = (float)rb[3];
    } else {
      r4 = ((const float4*)((const float*)resid + (size_t)row * DMODEL))[t];
    }
    v.x += b4.x + r4.x; v.y += b4.y + r4.y; v.z += b4.z + r4.z; v.w += b4.w + r4.w;
  }
  float s  = v.x + v.y + v.z + v.w;
  float s2 = v.x * v.x + v.y * v.y + v.z * v.z + v.w * v.w;
#pragma unroll
  for (int off = 1; off < 64; off <<= 1) {
    s  += __shfl_xor(s, off, 64);
    s2 += __shfl_xor(s2, off, 64);
  }
  __shared__ float ps[4], ps2[4];
  if ((t & 63) == 0) { ps[t >> 6] = s; ps2[t >> 6] = s2; }
  __syncthreads();
  s  = ps[0] + ps[1] + ps[2] + ps[3];
  s2 = ps2[0] + ps2[1] + ps2[2] + ps2[3];
  const float mu   = s * (1.f / 1024.f);
  const float var  = fmaxf(s2 * (1.f / 1024.f) - mu * mu, 0.f);
  const float rstd = rsqrtf(var + 1e-6f);
  const float4 g4 = ((const float4*)gam)[t];
  const float4 b4 = ((const float4*)bet)[t];
  float4 ov;
  ov.x = g4.x * (v.x - mu) * rstd + b4.x;
  ov.y = g4.y * (v.y - mu) * rstd + b4.y;
  ov.z = g4.z * (v.z - mu) * rstd + b4.z;
  ov.w = g4.w * (v.w - mu) * rstd + b4.w;
  if (of) ((float4*)(of + (size_t)row * DMODEL))[t] = ov;
  if (ob) {
    const bf16x4 o4 = {(bf16)ov.x, (bf16)ov.y, (bf16)ov.z, (bf16)ov.w};
    *(bf16x4*)(ob + (size_t)row * DMODEL + t * 4) = o4;
  }
}

// ---------------------------------------------------------------------------
// Fused prep: x->bf16 (blocks 0..4095), 6 weight transpose-converts
// (4096..16383), mask -> packed bf16 bias pairs (16384).
// mbp[b*1024 + kt*32 + li] = halfwords (bias(kt*64+li), bias(kt*64+32+li)),
// bias = 0xC6EA (bf16 ~ -29952) when masked else 0.
// ---------------------------------------------------------------------------
__global__ __launch_bounds__(256) void prep_k(
    const float* __restrict__ x, const float* __restrict__ Wq,
    const float* __restrict__ Wk, const float* __restrict__ Wv,
    const float* __restrict__ Wo, const float* __restrict__ W1,
    const float* __restrict__ W2, const void* __restrict__ mask,
    bf16* __restrict__ xb, bf16* __restrict__ WqkvT, bf16* __restrict__ WoT,
    bf16* __restrict__ W1T, bf16* __restrict__ W2T, unsigned* __restrict__ mbp)
{
  __shared__ float tile[32][33];
  __shared__ int s_gt1, s_f1;
  const int tid = threadIdx.x;
  const int id = blockIdx.x;

  if (id < 4096) {                       // f2b: x -> xb
    const int i = id * 256 + tid;
    const float4 v = ((const float4*)x)[i];
    const bf16x4 o = {(bf16)v.x, (bf16)v.y, (bf16)v.z, (bf16)v.w};
    *(bf16x4*)(xb + (size_t)i * 4) = o;
    return;
  }
  if (id == 16384) {                     // mask -> packed bias pairs
    if (tid == 0) { s_gt1 = 0; s_f1 = 0; }
    __syncthreads();
    const unsigned* wds = (const unsigned*)mask;
    int gt1 = 0, f1 = 0;
    for (int i = tid; i < 1024; i += 256) {
      const unsigned xw = wds[i];
      gt1 |= (xw > 1u);
      f1  |= (xw == 0x3F800000u);
    }
    if (gt1) atomicOr(&s_gt1, 1);
    if (f1)  atomicOr(&s_f1, 1);
    __syncthreads();
    const int md = s_f1 ? 2 : (s_gt1 ? 1 : 0);  // 2=f32, 1=u8, 0=i32
    auto mbit = [&](int e) -> unsigned {
      if (md == 1)      return (((const unsigned char*)mask)[e] != 0);
      else if (md == 2) return (((const float*)mask)[e] != 0.f);
      else              return (((const int*)mask)[e] != 0);
    };
    for (int idx = tid; idx < 2048; idx += 256) {
      const int b = idx >> 10, kt = (idx >> 5) & 31, li = idx & 31;
      const int base = b * S_LEN + kt * 64 + li;
      const unsigned h0 = mbit(base)      ? 0xC6EAu : 0u;
      const unsigned h1 = mbit(base + 32) ? 0xC6EAu : 0u;
      mbp[idx] = h0 | (h1 << 16);
    }
    return;
  }
  const float* src; bf16* dst; int K, N, bx, by;
  if (id < 7168) {
    int s2 = id - 4096; const int wq = s2 >> 10; s2 &= 1023;
    src = wq == 0 ? Wq : (wq == 1 ? Wk : Wv);
    dst = WqkvT + (size_t)wq * DMODEL * DMODEL;
    K = 1024; N = 1024; bx = s2 & 31; by = s2 >> 5;
  } else if (id < 8192) {
    const int s2 = id - 7168;
    src = Wo; dst = WoT; K = 1024; N = 1024; bx = s2 & 31; by = s2 >> 5;
  } else if (id < 12288) {
    const int s2 = id - 8192;
    src = W1; dst = W1T; K = 1024; N = 4096; bx = s2 & 127; by = s2 >> 7;
  } else {
    const int s2 = id - 12288;
    src = W2; dst = W2T; K = 4096; N = 1024; bx = s2 & 31; by = s2 >> 5;
  }
  const int tx = tid & 31, ty = tid >> 5;
  const int r0 = by * 32, c0 = bx * 32;
#pragma unroll
  for (int i = 0; i < 32; i += 8)
    tile[ty + i][tx] = src[(size_t)(r0 + ty + i) * N + c0 + tx];
  __syncthreads();
#pragma unroll
  for (int i = 0; i < 32; i += 8)
    dst[(size_t)(c0 + ty + i) * K + r0 + tx] = (bf16)tile[tx][ty + i];
}

// ---------------------------------------------------------------------------
extern "C" void kernel_launch(void* const* d_in, const int* in_sizes, int n_in,
                              void* d_out, int out_size, void* d_ws, size_t ws_size,
                              hipStream_t stream)
{
  const float* x    = (const float*)d_in[0];
  const void*  mask = d_in[1];
  const float* Wq   = (const float*)d_in[2];
  const float* Wk   = (const float*)d_in[3];
  const float* Wv   = (const float*)d_in[4];
  const float* Wo   = (const float*)d_in[5];
  const float* bo   = (const float*)d_in[6];
  const float* W1   = (const float*)d_in[7];
  const float* b1   = (const float*)d_in[8];
  const float* W2   = (const float*)d_in[9];
  const float* b2   = (const float*)d_in[10];
  const float* g1   = (const float*)d_in[11];
  const float* m1   = (const float*)d_in[12];
  const float* g2   = (const float*)d_in[13];
  const float* m2   = (const float*)d_in[14];

  const size_t plane = (size_t)NTOK * DMODEL;   // 4M elems

  char* ws = (char*)d_ws;
  size_t off = 0;
  auto alloc = [&](size_t bytes) {
    char* p = ws + off;
    off += (bytes + 255) & ~(size_t)255;
    return p;
  };
  bf16* xb     = (bf16*)alloc(plane * 2);                       // 8MB
  bf16* WqkvT  = (bf16*)alloc((size_t)3 * DMODEL * DMODEL * 2); // 6MB
  bf16* WoT    = (bf16*)alloc((size_t)DMODEL * DMODEL * 2);     // 2MB
  bf16* W1T    = (bf16*)alloc((size_t)NFF * DMODEL * 2);        // 8MB [4096][1024]
  bf16* W2T    = (bf16*)alloc((size_t)DMODEL * NFF * 2);        // 8MB [1024][4096]
  bf16* qkv    = (bf16*)alloc(4 * plane * 2);                   // 32MB
  bf16* qb = qkv, *kb = qkv + plane, *vtb = qkv + 2 * plane, *ctxb = qkv + 3 * plane;
  bf16* hb     = qkv;               // alias: qkv dead after Wo gemm
  float* parts = (float*)alloc(4 * plane * 4);                  // 64MB
  bf16*  x1b   = (bf16*)alloc(plane * 2);                       // 8MB
  unsigned* mbp = (unsigned*)alloc(8192);                       // [B][32][32] u32

  // 1) fused prep (x->bf16, 6 weight transposes, mask bias pairs): one dispatch
  prep_k<<<dim3(16385), dim3(256), 0, stream>>>(
      x, Wq, Wk, Wv, Wo, W1, W2, mask, xb, WqkvT, WoT, W1T, W2T, mbp);

  // 2) fused QKV projection: N=3072, 768 blocks (3/CU), XCD-swizzled
  gemm_bt<0><<<dim3(768), dim3(256), 0, stream>>>(
      xb, WqkvT, qkv, nullptr, NTOK, 3 * DMODEL, DMODEL, DMODEL, 24, 32);

  // 3) attention (8 warps x 32 q-rows, 256 blocks, XCD-affine heads)
  attn_k<<<dim3(256), dim3(512), 0, stream>>>(qb, kb, vtb, mbp, ctxb);

  // 4) output proj (split-K=2, Kc=512, 512 blocks) + LN1 (reduce + bo + xb)
  gemm_bt<4><<<dim3(512), dim3(256), 0, stream>>>(
      ctxb, WoT, parts, nullptr, NTOK, DMODEL, DMODEL, DMODEL / 2, 8, 32);
  ln_k<2, 1><<<dim3(NTOK), dim3(256), 0, stream>>>(parts, bo, xb, g1, m1, nullptr, x1b);

  // 5) FFN1 (relu+bias, 1024 blocks), FFN2 (split-K=4, Kc=1024, 1024 blocks),
  //    LN2 (bf16 resid) -> d_out
  gemm_bt<3><<<dim3(1024), dim3(256), 0, stream>>>(
      x1b, W1T, hb, b1, NTOK, NFF, DMODEL, DMODEL, 32, 32);
  gemm_bt<4><<<dim3(1024), dim3(256), 0, stream>>>(
      hb, W2T, parts, nullptr, NTOK, DMODEL, NFF, NFF / 4, 8, 32);
  ln_k<4, 1><<<dim3(NTOK), dim3(256), 0, stream>>>(parts, b2, x1b, g2, m2, (float*)d_out, nullptr);
}

// Round 16
// 265.961 us; speedup vs baseline: 1.0369x; 1.0369x over previous
//
#include <hip/hip_runtime.h>
#include <hip/hip_bf16.h>

// Transformer encoder layer (post-LN), B=2 S=2048 D=1024 H=16 DH=64 FF=4096.
// m97 128^2 bf16 MFMA GEMMs (fused-QKV, split-K, XCD swizzle) + 8-warp 32x32
// swapped-QK^T flash attention (mask folded into QK^T MFMA as rank-1 bias,
// MFMA denominator, defer-max) + fp32 LN with fused split-K reduce.
// [R16 = revert to the best measured configuration, R12: 266.4 us]

typedef __bf16 bf16;
typedef __bf16 bf16x8 __attribute__((ext_vector_type(8)));
typedef __bf16 bf16x4 __attribute__((ext_vector_type(4)));
typedef float  f32x4  __attribute__((ext_vector_type(4)));
typedef float  f32x16 __attribute__((ext_vector_type(16)));
typedef unsigned u32x2 __attribute__((ext_vector_type(2)));
typedef unsigned u32x4 __attribute__((ext_vector_type(4)));

#define DEVI __device__ __forceinline__

constexpr int S_LEN  = 2048;
constexpr int NTOK   = 4096;   // B*S
constexpr int DMODEL = 1024;
constexpr int NFF    = 4096;
constexpr float SCALE2 = 0.125f * 1.44269504088896f;  // (1/sqrt(64)) * log2(e)

DEVI void gld16(const void* g, void* l) {
  __builtin_amdgcn_global_load_lds((const __attribute__((address_space(1))) void*)g,
                                   (__attribute__((address_space(3))) void*)l, 16, 0, 0);
}

DEVI f32x4 mfma16(bf16x8 a, bf16x8 b, f32x4 c) {
  return __builtin_amdgcn_mfma_f32_16x16x32_bf16(a, b, c, 0, 0, 0);
}
DEVI f32x16 mfma32(bf16x8 a, bf16x8 b, f32x16 c) {
  return __builtin_amdgcn_mfma_f32_32x32x16_bf16(a, b, c, 0, 0, 0);
}
DEVI unsigned cvtpk(float lo, float hi) {
  unsigned d;
  asm("v_cvt_pk_bf16_f32 %0, %1, %2" : "=v"(d) : "v"(lo), "v"(hi));
  return d;
}
DEVI void plswap(unsigned &a, unsigned &b) {
#if __has_builtin(__builtin_amdgcn_permlane32_swap)
  u32x2 r = __builtin_amdgcn_permlane32_swap(a, b, false, false);
  a = r[0]; b = r[1];
#else
  asm volatile("v_permlane32_swap_b32 %0, %1" : "+v"(a), "+v"(b));
#endif
}
DEVI float fexp2(float x) {
#if __has_builtin(__builtin_amdgcn_exp2f)
  return __builtin_amdgcn_exp2f(x);
#else
  return exp2f(x);
#endif
}
#define M3(a, b, c) fmaxf(fmaxf(a, b), c)

// ---------------------------------------------------------------------------
// m97 GEMM: C[M,N] = A[M,ld] @ Bt[N,ld]^T over K-chunk [kz*Kc,(kz+1)*Kc).
// 128x128 tile, BK=32, 4 waves (2x2 of 64x64). 1D grid, XCD-bijective swizzle.
// MODE 0: bf16 out = fused-QKV scatter (q scaled by SCALE2; v written ^T)
// MODE 3: bf16 out = relu(acc + bias[col]), row-major [M][N]
// MODE 4: f32 partial out[kz][M][N] = acc  (reduce fused into ln_k)
// ---------------------------------------------------------------------------
template <int MODE>
__global__ __launch_bounds__(256) void gemm_bt(
    const bf16* __restrict__ A, const bf16* __restrict__ Bt,
    void* __restrict__ out, const float* __restrict__ bias,
    int M, int N, int ld, int Kc, int nx, int ny)
{
  __shared__ bf16 As[128 * 32];
  __shared__ bf16 Bs[128 * 32];
  const int tid  = threadIdx.x;
  const int lane = tid & 63, w = tid >> 6;
  const int wr = w >> 1, wc = w & 1;

  // XCD-bijective remap (ny % 8 == 0 for all our shapes)
  const int id  = blockIdx.x;
  const int xcd = id & 7;
  int t2 = id >> 3;
  const int bx = t2 % nx;  t2 /= nx;
  const int ppx = ny >> 3;
  const int kz = t2 / ppx;
  const int by = xcd * ppx + (t2 % ppx);
  const int brow = by * 128, bcol = bx * 128;

  const bf16* Ag = A  + (size_t)(brow + w * 32 + (lane >> 2)) * ld + kz * Kc + (lane & 3) * 8;
  const bf16* Bg = Bt + (size_t)(bcol + w * 32 + (lane >> 2)) * ld + kz * Kc + (lane & 3) * 8;
  bf16* AsW = As + w * 1024;
  bf16* BsW = Bs + w * 1024;

  f32x4 acc[4][4] = {};

  for (int k0 = 0; k0 < Kc; k0 += 32) {
    gld16(Ag + k0,                    AsW);
    gld16(Ag + k0 + (size_t)16 * ld,  AsW + 512);
    gld16(Bg + k0,                    BsW);
    gld16(Bg + k0 + (size_t)16 * ld,  BsW + 512);
    __syncthreads();

    bf16x8 af[4], bfr[4];
#pragma unroll
    for (int m = 0; m < 4; ++m)
      af[m] = *(const bf16x8*)&As[(wr * 64 + m * 16 + (lane & 15)) * 32 + (lane >> 4) * 8];
#pragma unroll
    for (int n = 0; n < 4; ++n)
      bfr[n] = *(const bf16x8*)&Bs[(wc * 64 + n * 16 + (lane & 15)) * 32 + (lane >> 4) * 8];
    __builtin_amdgcn_s_setprio(1);
#pragma unroll
    for (int m = 0; m < 4; ++m)
#pragma unroll
      for (int n = 0; n < 4; ++n)
        acc[m][n] = mfma16(af[m], bfr[n], acc[m][n]);
    __builtin_amdgcn_s_setprio(0);
    __syncthreads();
  }

  const size_t plane = (size_t)NTOK * DMODEL;
#pragma unroll
  for (int m = 0; m < 4; ++m)
#pragma unroll
    for (int n = 0; n < 4; ++n)
#pragma unroll
      for (int r = 0; r < 4; ++r) {
        const int row = brow + wr * 64 + m * 16 + (lane >> 4) * 4 + r;
        const int col = bcol + wc * 64 + n * 16 + (lane & 15);
        const float v = acc[m][n][r];
        if (MODE == 0) {
          const int b = row >> 11, s = row & 2047;
          const int which = col >> 10, c = col & 1023, h = c >> 6, d = c & 63;
          bf16* qkv = (bf16*)out;
          if (which == 0)
            qkv[(((size_t)(b * 16 + h)) * 2048 + s) * 64 + d] = (bf16)(v * SCALE2);
          else if (which == 1)
            (qkv + plane)[(((size_t)(b * 16 + h)) * 2048 + s) * 64 + d] = (bf16)v;
          else
            (qkv + 2 * plane)[(((size_t)(b * 16 + h)) * 64 + d) * 2048 + s] = (bf16)v;
        } else if (MODE == 3) {
          const float t = v + bias[col];
          ((bf16*)out)[(size_t)row * N + col] = (bf16)fmaxf(t, 0.0f);
        } else {
          ((float*)out)[(size_t)kz * M * N + (size_t)row * N + col] = v;
        }
      }
}

// ---------------------------------------------------------------------------
// Flash attention, 8 warps x 32 q-rows, KVBLK=64, swapped QK^T (32x32 MFMA).
// 1D grid 256, XCD-affine heads. q pre-scaled. Mask folded into QK^T MFMA as
// rank-1 bias (A=bias[key], B=ones). MFMA denominator; defer-max.
// mbp[b][kt][li] = packed bf16 bias pair (key=kt*64+li, key=kt*64+32+li).
// ---------------------------------------------------------------------------
__global__ __launch_bounds__(512) void attn_k(
    const bf16* __restrict__ q, const bf16* __restrict__ k,
    const bf16* __restrict__ vt, const unsigned* __restrict__ mbp,
    bf16* __restrict__ ctx)
{
  __shared__ __align__(16) char smem[36864];   // K dbuf 16K | V dbuf 16K ; epi
  bf16* Kl = (bf16*)smem;                      // [2][64*64]
  bf16* Vl = (bf16*)(smem + 16384);            // [2][64*64]
  const int tid = threadIdx.x, lane = tid & 63, w = tid >> 6;
  const int hi = lane >> 5, li = lane & 31;
  const int id = blockIdx.x;
  const int j = id >> 3;
  const int bh = (id & 7) * 4 + (j & 3);       // XCD (id&7) owns heads 4*xcd..+3
  const int b = bh >> 4, h = bh & 15;
  const int qbase = (j >> 2) * 256 + w * 32;

  bf16x8 qf[4];
  {
    const bf16* qp = q + ((size_t)bh * S_LEN + qbase + li) * 64 + hi * 8;
#pragma unroll
    for (int c = 0; c < 4; ++c) qf[c] = *(const bf16x8*)(qp + c * 16);
  }
  const u32x4 onesu = {0x3F803F80u, 0x3F803F80u, 0x3F803F80u, 0x3F803F80u};
  const bf16x8 onesv = __builtin_bit_cast(bf16x8, onesu);
  // B operand for the rank-1 mask bias: B[k=0][q]=1 (lanes hi==0, elem 0)
  const u32x4 bq1 = {hi ? 0u : 0x3F80u, 0u, 0u, 0u};
  const bf16x8 bones = __builtin_bit_cast(bf16x8, bq1);

  f32x16 o[2] = {};
  f32x16 acc1 = {};                  // element 0 = softmax denominator (q = li)
  float mrun = -3.0e38f;

  const int srow = w * 8 + (lane >> 3);
  const int sslot = (lane & 7) ^ ((srow ^ (srow >> 3)) & 7);
  const bf16* kg = k  + ((size_t)bh * S_LEN + srow) * 64 + sslot * 8;
  const bf16* vg = vt + ((size_t)bh * 64 + srow) * S_LEN + sslot * 8;

  gld16(kg, Kl + w * 512);
  gld16(vg, Vl + w * 512);
  __syncthreads();

  int buf = 0;
  for (int kt = 0; kt < 32; ++kt) {
    const int nb = buf ^ 1;
    if (kt + 1 < 32) {
      gld16(kg + (size_t)(kt + 1) * 4096, Kl + nb * 4096 + w * 512);
      gld16(vg + (kt + 1) * 64,           Vl + nb * 4096 + w * 512);
    }
    const unsigned mbw = mbp[b * 1024 + kt * 32 + li];
    const bf16* Kb = Kl + buf * 4096;
    const bf16* Vb = Vl + buf * 4096;

    float sc[2][16];
#pragma unroll
    for (int kblk = 0; kblk < 2; ++kblk) {
      const int key = kblk * 32 + li;
      const unsigned swb = ((key ^ (key >> 3)) & 7) << 4;
      const char* kr = (const char*)Kb + key * 128;
      // rank-1 mask bias: st = bias[key] broadcast over q
      const unsigned hw = kblk ? (mbw >> 16) : (mbw & 0xffffu);
      const u32x4 aq = {hi ? 0u : hw, 0u, 0u, 0u};
      f32x16 st = mfma32(__builtin_bit_cast(bf16x8, aq), bones, (f32x16){});
      __builtin_amdgcn_s_setprio(1);
#pragma unroll
      for (int c = 0; c < 4; ++c) {
        const bf16x8 kf = *(const bf16x8*)(kr + ((unsigned)(c * 32 + hi * 16) ^ swb));
        st = mfma32(kf, qf[c], st);
      }
      __builtin_amdgcn_s_setprio(0);
#pragma unroll
      for (int r = 0; r < 16; ++r) sc[kblk][r] = st[r];
    }

    const float* sf = &sc[0][0];
    float m0[11];
#pragma unroll
    for (int i3 = 0; i3 < 10; ++i3) m0[i3] = M3(sf[i3 * 3], sf[i3 * 3 + 1], sf[i3 * 3 + 2]);
    m0[10] = fmaxf(sf[30], sf[31]);
    float tm = fmaxf(fmaxf(M3(m0[0], m0[1], m0[2]), M3(m0[3], m0[4], m0[5])),
                     fmaxf(M3(m0[6], m0[7], m0[8]), fmaxf(m0[9], m0[10])));
    tm = fmaxf(tm, __shfl_xor(tm, 32, 64));

    if (!__all(tm <= mrun + 11.0f)) {
      const float mnew = fmaxf(mrun, tm);
      const float alpha = fexp2(mrun - mnew);
      mrun = mnew;
      o[0] *= alpha;
      o[1] *= alpha;
      acc1[0] = acc1[0] * alpha;
    }
#pragma unroll
    for (int kblk = 0; kblk < 2; ++kblk)
#pragma unroll
      for (int r = 0; r < 16; ++r)
        sc[kblk][r] = fexp2(sc[kblk][r] - mrun);

    bf16x8 pa[4];
#pragma unroll
    for (int kblk = 0; kblk < 2; ++kblk)
#pragma unroll
      for (int hf = 0; hf < 2; ++hf) {
        unsigned A = cvtpk(sc[kblk][hf * 8 + 0], sc[kblk][hf * 8 + 1]);
        unsigned B = cvtpk(sc[kblk][hf * 8 + 2], sc[kblk][hf * 8 + 3]);
        unsigned C = cvtpk(sc[kblk][hf * 8 + 4], sc[kblk][hf * 8 + 5]);
        unsigned D = cvtpk(sc[kblk][hf * 8 + 6], sc[kblk][hf * 8 + 7]);
        plswap(A, C);
        plswap(B, D);
        const u32x4 t = {A, B, C, D};
        pa[kblk * 2 + hf] = __builtin_bit_cast(bf16x8, t);
      }

#pragma unroll
    for (int dblk = 0; dblk < 2; ++dblk) {
      const int d = dblk * 32 + li;
      const unsigned swb = ((d ^ (d >> 3)) & 7) << 4;
      const char* vr = (const char*)Vb + d * 128;
      __builtin_amdgcn_s_setprio(1);
#pragma unroll
      for (int ch = 0; ch < 4; ++ch) {
        const bf16x8 vf = *(const bf16x8*)(vr + ((unsigned)(ch * 32 + hi * 16) ^ swb));
        o[dblk] = mfma32(vf, pa[ch], o[dblk]);
      }
      __builtin_amdgcn_s_setprio(0);
    }
#pragma unroll
    for (int ch = 0; ch < 4; ++ch) acc1 = mfma32(onesv, pa[ch], acc1);
    __syncthreads();
    buf = nb;
  }

  const float rl = 1.0f / acc1[0];
  char* Ep = smem + w * 4608;
#pragma unroll
  for (int dblk = 0; dblk < 2; ++dblk)
#pragma unroll
    for (int g = 0; g < 4; ++g) {
      const unsigned lo = cvtpk(o[dblk][4 * g + 0] * rl, o[dblk][4 * g + 1] * rl);
      const unsigned hw = cvtpk(o[dblk][4 * g + 2] * rl, o[dblk][4 * g + 3] * rl);
      const int d0 = 8 * g + 4 * hi + 32 * dblk;
      *(unsigned long long*)(Ep + li * 144 + d0 * 2) =
          ((unsigned long long)hw << 32) | (unsigned long long)lo;
    }
#pragma unroll
  for (int i = 0; i < 4; ++i) {
    const int r = (lane >> 3) + 8 * i;
    const bf16x8 vv = *(const bf16x8*)(Ep + r * 144 + (lane & 7) * 16);
    *(bf16x8*)(ctx + ((size_t)b * S_LEN + qbase + r) * DMODEL + h * 64 + (lane & 7) * 8) = vv;
  }
}

// ---------------------------------------------------------------------------
// LayerNorm over D=1024 with fused split-K reduce + bias + residual.
// RB=1: residual is bf16. grid = 4096 rows, block = 256 (float4 per thread).
// ---------------------------------------------------------------------------
template <int NPART, int RB>
__global__ __launch_bounds__(256) void ln_k(
    const float* __restrict__ parts, const float* __restrict__ bias,
    const void* __restrict__ resid, const float* __restrict__ gam,
    const float* __restrict__ bet, float* __restrict__ of, bf16* __restrict__ ob)
{
  const int row = blockIdx.x, t = threadIdx.x;
  float4 v = ((const float4*)(parts + (size_t)row * DMODEL))[t];
#pragma unroll
  for (int p = 1; p < NPART; ++p) {
    const float4 u = ((const float4*)(parts + ((size_t)p * NTOK + row) * DMODEL))[t];
    v.x += u.x; v.y += u.y; v.z += u.z; v.w += u.w;
  }
  {
    const float4 b4 = ((const float4*)bias)[t];
    float4 r4;
    if (RB) {
      const bf16x4 rb = *(const bf16x4*)((const bf16*)resid + (size_t)row * DMODEL + t * 4);
      r4.x = (float)rb[0]; r4.y = (float)rb[1]; r4.z = (float)rb[2]; r4.w = (float)rb[3];
    } else {
      r4 = ((const float4*)((const float*)resid + (size_t)row * DMODEL))[t];
    }
    v.x += b4.x + r4.x; v.y += b4.y + r4.y; v.z += b4.z + r4.z; v.w += b4.w + r4.w;
  }
  float s  = v.x + v.y + v.z + v.w;
  float s2 = v.x * v.x + v.y * v.y + v.z * v.z + v.w * v.w;
#pragma unroll
  for (int off = 1; off < 64; off <<= 1) {
    s  += __shfl_xor(s, off, 64);
    s2 += __shfl_xor(s2, off, 64);
  }
  __shared__ float ps[4], ps2[4];
  if ((t & 63) == 0) { ps[t >> 6] = s; ps2[t >> 6] = s2; }
  __syncthreads();
  s  = ps[0] + ps[1] + ps[2] + ps[3];
  s2 = ps2[0] + ps2[1] + ps2[2] + ps2[3];
  const float mu   = s * (1.f / 1024.f);
  const float var  = fmaxf(s2 * (1.f / 1024.f) - mu * mu, 0.f);
  const float rstd = rsqrtf(var + 1e-6f);
  const float4 g4 = ((const float4*)gam)[t];
  const float4 b4 = ((const float4*)bet)[t];
  float4 ov;
  ov.x = g4.x * (v.x - mu) * rstd + b4.x;
  ov.y = g4.y * (v.y - mu) * rstd + b4.y;
  ov.z = g4.z * (v.z - mu) * rstd + b4.z;
  ov.w = g4.w * (v.w - mu) * rstd + b4.w;
  if (of) ((float4*)(of + (size_t)row * DMODEL))[t] = ov;
  if (ob) {
    const bf16x4 o4 = {(bf16)ov.x, (bf16)ov.y, (bf16)ov.z, (bf16)ov.w};
    *(bf16x4*)(ob + (size_t)row * DMODEL + t * 4) = o4;
  }
}

// ---------------------------------------------------------------------------
// Fused prep: x->bf16 (blocks 0..4095), 6 weight transpose-converts
// (4096..16383), mask -> packed bf16 bias pairs (16384).
// mbp[b*1024 + kt*32 + li] = halfwords (bias(kt*64+li), bias(kt*64+32+li)),
// bias = 0xC6EA (bf16 ~ -29952) when masked else 0.
// ---------------------------------------------------------------------------
__global__ __launch_bounds__(256) void prep_k(
    const float* __restrict__ x, const float* __restrict__ Wq,
    const float* __restrict__ Wk, const float* __restrict__ Wv,
    const float* __restrict__ Wo, const float* __restrict__ W1,
    const float* __restrict__ W2, const void* __restrict__ mask,
    bf16* __restrict__ xb, bf16* __restrict__ WqkvT, bf16* __restrict__ WoT,
    bf16* __restrict__ W1T, bf16* __restrict__ W2T, unsigned* __restrict__ mbp)
{
  __shared__ float tile[32][33];
  __shared__ int s_gt1, s_f1;
  const int tid = threadIdx.x;
  const int id = blockIdx.x;

  if (id < 4096) {                       // f2b: x -> xb
    const int i = id * 256 + tid;
    const float4 v = ((const float4*)x)[i];
    const bf16x4 o = {(bf16)v.x, (bf16)v.y, (bf16)v.z, (bf16)v.w};
    *(bf16x4*)(xb + (size_t)i * 4) = o;
    return;
  }
  if (id == 16384) {                     // mask -> packed bias pairs
    if (tid == 0) { s_gt1 = 0; s_f1 = 0; }
    __syncthreads();
    const unsigned* wds = (const unsigned*)mask;
    int gt1 = 0, f1 = 0;
    for (int i = tid; i < 1024; i += 256) {
      const unsigned xw = wds[i];
      gt1 |= (xw > 1u);
      f1  |= (xw == 0x3F800000u);
    }
    if (gt1) atomicOr(&s_gt1, 1);
    if (f1)  atomicOr(&s_f1, 1);
    __syncthreads();
    const int md = s_f1 ? 2 : (s_gt1 ? 1 : 0);  // 2=f32, 1=u8, 0=i32
    auto mbit = [&](int e) -> unsigned {
      if (md == 1)      return (((const unsigned char*)mask)[e] != 0);
      else if (md == 2) return (((const float*)mask)[e] != 0.f);
      else              return (((const int*)mask)[e] != 0);
    };
    for (int idx = tid; idx < 2048; idx += 256) {
      const int b = idx >> 10, kt = (idx >> 5) & 31, li = idx & 31;
      const int base = b * S_LEN + kt * 64 + li;
      const unsigned h0 = mbit(base)      ? 0xC6EAu : 0u;
      const unsigned h1 = mbit(base + 32) ? 0xC6EAu : 0u;
      mbp[idx] = h0 | (h1 << 16);
    }
    return;
  }
  const float* src; bf16* dst; int K, N, bx, by;
  if (id < 7168) {
    int s2 = id - 4096; const int wq = s2 >> 10; s2 &= 1023;
    src = wq == 0 ? Wq : (wq == 1 ? Wk : Wv);
    dst = WqkvT + (size_t)wq * DMODEL * DMODEL;
    K = 1024; N = 1024; bx = s2 & 31; by = s2 >> 5;
  } else if (id < 8192) {
    const int s2 = id - 7168;
    src = Wo; dst = WoT; K = 1024; N = 1024; bx = s2 & 31; by = s2 >> 5;
  } else if (id < 12288) {
    const int s2 = id - 8192;
    src = W1; dst = W1T; K = 1024; N = 4096; bx = s2 & 127; by = s2 >> 7;
  } else {
    const int s2 = id - 12288;
    src = W2; dst = W2T; K = 4096; N = 1024; bx = s2 & 31; by = s2 >> 5;
  }
  const int tx = tid & 31, ty = tid >> 5;
  const int r0 = by * 32, c0 = bx * 32;
#pragma unroll
  for (int i = 0; i < 32; i += 8)
    tile[ty + i][tx] = src[(size_t)(r0 + ty + i) * N + c0 + tx];
  __syncthreads();
#pragma unroll
  for (int i = 0; i < 32; i += 8)
    dst[(size_t)(c0 + ty + i) * K + r0 + tx] = (bf16)tile[tx][ty + i];
}

// ---------------------------------------------------------------------------
extern "C" void kernel_launch(void* const* d_in, const int* in_sizes, int n_in,
                              void* d_out, int out_size, void* d_ws, size_t ws_size,
                              hipStream_t stream)
{
  const float* x    = (const float*)d_in[0];
  const void*  mask = d_in[1];
  const float* Wq   = (const float*)d_in[2];
  const float* Wk   = (const float*)d_in[3];
  const float* Wv   = (const float*)d_in[4];
  const float* Wo   = (const float*)d_in[5];
  const float* bo   = (const float*)d_in[6];
  const float* W1   = (const float*)d_in[7];
  const float* b1   = (const float*)d_in[8];
  const float* W2   = (const float*)d_in[9];
  const float* b2   = (const float*)d_in[10];
  const float* g1   = (const float*)d_in[11];
  const float* m1   = (const float*)d_in[12];
  const float* g2   = (const float*)d_in[13];
  const float* m2   = (const float*)d_in[14];

  const size_t plane = (size_t)NTOK * DMODEL;   // 4M elems

  char* ws = (char*)d_ws;
  size_t off = 0;
  auto alloc = [&](size_t bytes) {
    char* p = ws + off;
    off += (bytes + 255) & ~(size_t)255;
    return p;
  };
  bf16* xb     = (bf16*)alloc(plane * 2);                       // 8MB
  bf16* WqkvT  = (bf16*)alloc((size_t)3 * DMODEL * DMODEL * 2); // 6MB
  bf16* WoT    = (bf16*)alloc((size_t)DMODEL * DMODEL * 2);     // 2MB
  bf16* W1T    = (bf16*)alloc((size_t)NFF * DMODEL * 2);        // 8MB [4096][1024]
  bf16* W2T    = (bf16*)alloc((size_t)DMODEL * NFF * 2);        // 8MB [1024][4096]
  bf16* qkv    = (bf16*)alloc(4 * plane * 2);                   // 32MB
  bf16* qb = qkv, *kb = qkv + plane, *vtb = qkv + 2 * plane, *ctxb = qkv + 3 * plane;
  bf16* hb     = qkv;               // alias: qkv dead after Wo gemm
  float* parts = (float*)alloc(4 * plane * 4);                  // 64MB
  bf16*  x1b   = (bf16*)alloc(plane * 2);                       // 8MB
  unsigned* mbp = (unsigned*)alloc(8192);                       // [B][32][32] u32

  // 1) fused prep (x->bf16, 6 weight transposes, mask bias pairs): one dispatch
  prep_k<<<dim3(16385), dim3(256), 0, stream>>>(
      x, Wq, Wk, Wv, Wo, W1, W2, mask, xb, WqkvT, WoT, W1T, W2T, mbp);

  // 2) fused QKV projection: N=3072, 768 blocks (3/CU), XCD-swizzled
  gemm_bt<0><<<dim3(768), dim3(256), 0, stream>>>(
      xb, WqkvT, qkv, nullptr, NTOK, 3 * DMODEL, DMODEL, DMODEL, 24, 32);

  // 3) attention (8 warps x 32 q-rows, 256 blocks, XCD-affine heads)
  attn_k<<<dim3(256), dim3(512), 0, stream>>>(qb, kb, vtb, mbp, ctxb);

  // 4) output proj (split-K=2, 512 blocks) + LN1 (fused reduce + bo + xb)
  gemm_bt<4><<<dim3(512), dim3(256), 0, stream>>>(
      ctxb, WoT, parts, nullptr, NTOK, DMODEL, DMODEL, DMODEL / 2, 8, 32);
  ln_k<2, 1><<<dim3(NTOK), dim3(256), 0, stream>>>(parts, bo, xb, g1, m1, nullptr, x1b);

  // 5) FFN1 (relu+bias, 1024 blocks), FFN2 (split-K=4, 1024 blocks),
  //    LN2 (bf16 resid) -> d_out
  gemm_bt<3><<<dim3(1024), dim3(256), 0, stream>>>(
      x1b, W1T, hb, b1, NTOK, NFF, DMODEL, DMODEL, 32, 32);
  gemm_bt<4><<<dim3(1024), dim3(256), 0, stream>>>(
      hb, W2T, parts, nullptr, NTOK, DMODEL, NFF, NFF / 4, 8, 32);
  ln_k<4, 1><<<dim3(NTOK), dim3(256), 0, stream>>>(parts, b2, x1b, g2, m2, (float*)d_out, nullptr);
}